// Round 1
// baseline (203.218 us; speedup 1.0000x reference)
//
#include <hip/hip_runtime.h>

// RoIAlign, fused single-kernel version.
//   One thread per float4 of channels; 64 lanes = one (n,i,j) cell.
//   n = (idx>>6)/49 is wave-uniform -> readfirstlane scalarizes the rois
//   loads and the level select; per-ROI params are recomputed inline
//   (~30 VALU ops/wave, hidden under the output store). This removes the
//   former params kernel, its launch+dependency gap, and the d_ws round-trip.
// Quirk reproduced from the reference: boxes fed as [x1,y1,x2,y2]/stride but
// consumed as normalized [y1,x1,y2,x2] and rescaled by (H-1) -> nearly all
// sample points invalid -> zero output. fp contract off everywhere so the
// mul/add rounding matches the unfused jax reference exactly (same op order
// as the previously-passing two-kernel version: absmax 0.0).

constexpr int CH = 256;

typedef float v4f __attribute__((ext_vector_type(4)));

__global__ __launch_bounds__(256)
void roi_align_fused(const float* __restrict__ p2, const float* __restrict__ p3,
                     const float* __restrict__ p4, const float* __restrict__ p5,
                     const float* __restrict__ rois,
                     float* __restrict__ out, int nrois)
{
#pragma clang fp contract(off)
    int idx = blockIdx.x * blockDim.x + threadIdx.x;
    int total = nrois * 49 * 64;
    if (idx >= total) return;

    int c4   = idx & 63;
    int t    = idx >> 6;
    int n    = t / 49;
    int cell = t - n * 49;
    int i    = cell / 7;
    int j    = cell - i * 7;

    // Wave-uniform ROI index: block=256, wave=64 consecutive idx values,
    // so idx>>6 (and hence n) is constant across the wave. readfirstlane
    // lets the compiler use s_load for the rois row and s_cbranch for level.
    int ns = __builtin_amdgcn_readfirstlane(n);
    const float* r = rois + ns * 5;
    int   b  = (int)r[0];
    float x1 = r[1], y1 = r[2], x2 = r[3], y2 = r[4];

    // level = clip(round(4 + log2(sqrt(h*w)/224)), 2, 5); rintf = RNE like jnp.round
    float lvl = 4.0f + log2f(sqrtf((y2 - y1) * (x2 - x1)) / 224.0f);
    int level = (int)rintf(lvl);
    level = level < 2 ? 2 : (level > 5 ? 5 : level);

    int H; float inv_s;
    const float* fm;
    if (level == 2)      { H = 256; inv_s = 0.25f;    fm = p2; }
    else if (level == 3) { H = 128; inv_s = 0.125f;   fm = p3; }
    else if (level == 4) { H = 64;  inv_s = 0.0625f;  fm = p4; }
    else                 { H = 32;  inv_s = 0.03125f; fm = p5; }

    // Quirk: [x1,y1,x2,y2]*inv_s read as [y1,x1,y2,x2]
    float cy1 = x1 * inv_s, cx1 = y1 * inv_s;
    float cy2 = x2 * inv_s, cx2 = y2 * inv_s;
    float Hm1 = (float)(H - 1);
    float h_scale = (cy2 - cy1) * Hm1 / 6.0f;   // ((dy)*Hm1)/6, left-to-right
    float w_scale = (cx2 - cx1) * Hm1 / 6.0f;

    // contract off: each mul and add individually rounded, matching jnp
    float in_y = cy1 * Hm1 + (float)i * h_scale;
    float in_x = cx1 * Hm1 + (float)j * w_scale;

    v4f* op = (v4f*)out + idx;   // idx == (t*64 + c4), dense float4 index

    bool valid = (in_y >= 0.0f) & (in_y <= Hm1) & (in_x >= 0.0f) & (in_x <= Hm1);
    if (!valid) {
        v4f z; z.x = 0.f; z.y = 0.f; z.z = 0.f; z.w = 0.f;
        __builtin_nontemporal_store(z, op);
        return;
    }

    float fy = floorf(in_y), fx = floorf(in_x);
    // valid => floor/ceil already land in [0, H-1]; clamps kept (2 instrs, safety)
    int y0 = (int)fminf(fmaxf(fy, 0.f), Hm1);
    int yc = (int)fminf(fmaxf(ceilf(in_y), 0.f), Hm1);
    int x0 = (int)fminf(fmaxf(fx, 0.f), Hm1);
    int xc = (int)fminf(fmaxf(ceilf(in_x), 0.f), Hm1);
    float ly = in_y - fy, lx = in_x - fx;

    const float* img = fm + (size_t)b * H * H * CH;
    const v4f vtl = *((const v4f*)(img + ((size_t)y0 * H + x0) * CH) + c4);
    const v4f vtr = *((const v4f*)(img + ((size_t)y0 * H + xc) * CH) + c4);
    const v4f vbl = *((const v4f*)(img + ((size_t)yc * H + x0) * CH) + c4);
    const v4f vbr = *((const v4f*)(img + ((size_t)yc * H + xc) * CH) + c4);

    v4f res;
    {
        v4f top, bot;
        top = vtl + (vtr - vtl) * lx;
        bot = vbl + (vbr - vbl) * lx;
        res = top + (bot - top) * ly;
    }
    __builtin_nontemporal_store(res, op);
}

extern "C" void kernel_launch(void* const* d_in, const int* in_sizes, int n_in,
                              void* d_out, int out_size, void* d_ws, size_t ws_size,
                              hipStream_t stream)
{
    const float* p2   = (const float*)d_in[0];
    const float* p3   = (const float*)d_in[1];
    const float* p4   = (const float*)d_in[2];
    const float* p5   = (const float*)d_in[3];
    const float* rois = (const float*)d_in[4];
    float* out = (float*)d_out;
    (void)d_ws; (void)ws_size;

    int nrois = in_sizes[4] / 5;
    int total = nrois * 49 * 64;   // 1000*49*64 = 3,136,000 -> exactly 12250 blocks
    roi_align_fused<<<(total + 255) / 256, 256, 0, stream>>>(p2, p3, p4, p5,
                                                             rois, out, nrois);
}